// Round 3
// baseline (1900.806 us; speedup 1.0000x reference)
//
#include <hip/hip_runtime.h>
#include <hip/hip_fp16.h>

// B=256,S=256,T=32,H=512,E=128,V=1000,A=8,NT=80.
// Math: decoder is dead code (softmax shift-invariance over S) -> outputs are
// pa/pt tiled over T. Remaining: 256 serial LSTM steps + attention readout.
//
// Structure: 16 batch-groups x (16 rows, 16 wgs); each wg owns 128 z-cols with
// Wh weights in registers (bf16); h exchanged through L3 via agent-scope
// atomics; activations hi/lo bf16 split (2 MFMAs ~ fp32).
// R1: __threadfence -> buffer_wbl2+inv nuked L2 every step (13 us/step). Fixed.
// R2: 6.8 us/step, latency-bound on the barrier chain. This round:
//  - x-part precomputed as P = embed@Wi.T + b (gather, fp32 exact, prefetched)
//  - flag-line barrier (no RMW serialization; 64-lane parallel poll)
//  - 8B packed h stores (256/wg/step), c-state in registers

#define Bv 256
#define Sv 256
#define Tv 32
#define Hv 512
#define KT 16          // k-tiles of 32 over K=512 (h only; x-part via P gather)
#define LDSA 520       // padded k-stride (shorts); 260 dwords % 32 = 4 -> clean b128 pattern
#define GM 16          // batch rows per group
#define WPG 16         // workgroups per group

typedef __attribute__((ext_vector_type(8))) short bf16x8;
typedef __attribute__((ext_vector_type(4))) float f32x4;

__device__ __forceinline__ unsigned short f2bf(float x) {   // RNE fp32->bf16
  unsigned u = __builtin_bit_cast(unsigned, x);
  u += 0x7fffu + ((u >> 16) & 1u);
  return (unsigned short)(u >> 16);
}
__device__ __forceinline__ float bf2f(unsigned short h) {
  unsigned u = ((unsigned)h) << 16;
  return __builtin_bit_cast(float, u);
}
__device__ __forceinline__ float sigm(float x) { return 1.0f / (1.0f + __expf(-x)); }
__device__ __forceinline__ float tanh_fast(float x) {
  x = fminf(15.f, fmaxf(-15.f, x));
  float e = __expf(2.f * x);
  return (e - 1.f) / (e + 1.f);
}

// ---- P[v][n] = sum_k embed[v][k]*Wi[n][k] + be[n], fp32. 250 blocks x 4 tokens.
__global__ __launch_bounds__(256)
void build_P(const float* __restrict__ embed, const float* __restrict__ Wi,
             const float* __restrict__ be, float* __restrict__ P)
{
  __shared__ float ev[4][128];
  const int tid = threadIdx.x;
  const int v0  = blockIdx.x * 4;
#pragma unroll
  for (int i = 0; i < 2; ++i) {
    int e = tid + i * 256;
    ev[e >> 7][e & 127] = embed[(v0 + (e >> 7)) * 128 + (e & 127)];
  }
  __syncthreads();
#pragma unroll 1
  for (int cc = 0; cc < 8; ++cc) {
    int n = cc * 256 + tid;
    float b = be[n];
    float a0 = b, a1 = b, a2 = b, a3 = b;
    const f32x4* w = (const f32x4*)(Wi + n * 128);
#pragma unroll
    for (int k4 = 0; k4 < 32; ++k4) {
      f32x4 wv = w[k4];
#pragma unroll
      for (int j = 0; j < 4; ++j) {
        float wj = wv[j];
        int k = k4 * 4 + j;
        a0 += wj * ev[0][k]; a1 += wj * ev[1][k];
        a2 += wj * ev[2][k]; a3 += wj * ev[3][k];
      }
    }
    P[(size_t)(v0 + 0) * 2048 + n] = a0;
    P[(size_t)(v0 + 1) * 2048 + n] = a1;
    P[(size_t)(v0 + 2) * 2048 + n] = a2;
    P[(size_t)(v0 + 3) * 2048 + n] = a3;
  }
}

// hbuf: per group g, parity p: [16 rows][512 cols] packed (bf16_hi | bf16_lo<<16).
// flags: flags[g*16 + cb] = last step this wg finished (one 64B line per group).
__global__ __launch_bounds__(256, 2)
void lstm_enc(const int* __restrict__ enc_in, const float* __restrict__ P,
              const float* __restrict__ Wh,
              unsigned* __restrict__ flags, unsigned* __restrict__ hbuf,
              __half* __restrict__ enc_out)
{
  __shared__ __attribute__((aligned(16))) short Ahi[GM][LDSA];
  __shared__ __attribute__((aligned(16))) short Alo[GM][LDSA];
  __shared__ float zbuf[4][GM][37];   // odd stride: 2-way banks in gates reads

  const int tid  = threadIdx.x;
  const int wg   = blockIdx.x;
  const int g    = wg & 15;   // group (members share wg%8 -> same XCD heuristically)
  const int cb   = wg >> 4;   // column block: owns z-cols [q*512 + cb*32, +32) per gate q
  const int wave = tid >> 6;  // wave == gate q (0=i,1=f,2=g,3=o)
  const int lane = tid & 63;
  const int m16  = lane & 15;
  const int qd   = lane >> 4;

  // ---- Wh fragments in registers: lane holds W'[n][k] for
  // n = wave*512 + cb*32 + nt*16 + m16, k = kt*32 + qd*8 + j (j=0..7).
  bf16x8 wf[KT][2];
#pragma unroll
  for (int kt = 0; kt < KT; ++kt) {
#pragma unroll
    for (int nt = 0; nt < 2; ++nt) {
      int n  = wave * 512 + cb * 32 + nt * 16 + m16;
      int k0 = kt * 32 + qd * 8;
      const float* src = Wh + (size_t)n * Hv + k0;
      f32x4 f0 = *(const f32x4*)(src);
      f32x4 f1 = *(const f32x4*)(src + 4);
      bf16x8 w;
      w[0] = (short)f2bf(f0[0]); w[1] = (short)f2bf(f0[1]);
      w[2] = (short)f2bf(f0[2]); w[3] = (short)f2bf(f0[3]);
      w[4] = (short)f2bf(f1[0]); w[5] = (short)f2bf(f1[1]);
      w[6] = (short)f2bf(f1[2]); w[7] = (short)f2bf(f1[3]);
      wf[kt][nt] = w;
    }
  }

  // gates-phase mapping: thread owns (row gr, cols gj, gj+1); c-state in regs
  const int gr = tid >> 4;
  const int gj = (tid & 15) * 2;
  float c0 = 0.f, c1 = 0.f;

  unsigned* hb_g = hbuf + (size_t)g * (2 * GM * Hv);
  unsigned* flg  = flags + g * 16;

  // ---- P prefetch for s=0 (acc-layout rows r0..r0+3, cols ncol, ncol+16)
  const int r0   = qd * 4;
  const int ncol = wave * 512 + cb * 32 + m16;
  float px0[4], px1[4];
#pragma unroll
  for (int rr = 0; rr < 4; ++rr) {
    int tk  = enc_in[(g * GM + r0 + rr) * Sv + 0];
    px0[rr] = P[(size_t)tk * 2048 + ncol];
    px1[rr] = P[(size_t)tk * 2048 + ncol + 16];
  }

#pragma unroll 1
  for (int s = 0; s < Sv; ++s) {
    const int p = s & 1;

    // ---- stage h (parity p) via coherent 8B loads -> LDS hi/lo planes
    {
      const unsigned long long* hsrc =
          (const unsigned long long*)(hb_g + (size_t)p * (GM * Hv));
#pragma unroll
      for (int c = 0; c < 16; ++c) {
        unsigned long long v = __hip_atomic_load(hsrc + c * 256 + tid,
                                                 __ATOMIC_RELAXED, __HIP_MEMORY_SCOPE_AGENT);
        unsigned w0 = (unsigned)v, w1 = (unsigned)(v >> 32);
        unsigned hi2 = (w0 & 0xffffu) | (w1 << 16);
        unsigned lo2 = (w0 >> 16) | (w1 & 0xffff0000u);
        *(unsigned*)&Ahi[c][2 * tid] = hi2;
        *(unsigned*)&Alo[c][2 * tid] = lo2;
      }
    }
    __syncthreads();

    // ---- MFMA: z_h = (A_hi + A_lo) @ Wh^T
    f32x4 acc0 = {0.f, 0.f, 0.f, 0.f};
    f32x4 acc1 = {0.f, 0.f, 0.f, 0.f};
#pragma unroll
    for (int kt = 0; kt < KT; ++kt) {
      bf16x8 ah = *(const bf16x8*)&Ahi[m16][kt * 32 + qd * 8];
      bf16x8 al = *(const bf16x8*)&Alo[m16][kt * 32 + qd * 8];
      acc0 = __builtin_amdgcn_mfma_f32_16x16x32_bf16(ah, wf[kt][0], acc0, 0, 0, 0);
      acc0 = __builtin_amdgcn_mfma_f32_16x16x32_bf16(al, wf[kt][0], acc0, 0, 0, 0);
      acc1 = __builtin_amdgcn_mfma_f32_16x16x32_bf16(ah, wf[kt][1], acc1, 0, 0, 0);
      acc1 = __builtin_amdgcn_mfma_f32_16x16x32_bf16(al, wf[kt][1], acc1, 0, 0, 0);
    }
    // C/D layout: col = lane&15, row = (lane>>4)*4 + reg; add fp32 x-part (P)
#pragma unroll
    for (int rr = 0; rr < 4; ++rr) {
      zbuf[wave][r0 + rr][m16]      = acc0[rr] + px0[rr];
      zbuf[wave][r0 + rr][16 + m16] = acc1[rr] + px1[rr];
    }
    __syncthreads();

    // ---- gates for (gr, gj), (gr, gj+1)
    float i0 = zbuf[0][gr][gj], i1 = zbuf[0][gr][gj + 1];
    float f0g = zbuf[1][gr][gj], f1g = zbuf[1][gr][gj + 1];
    float g0 = zbuf[2][gr][gj], g1 = zbuf[2][gr][gj + 1];
    float o0 = zbuf[3][gr][gj], o1 = zbuf[3][gr][gj + 1];
    float cn0 = sigm(f0g) * c0 + sigm(i0) * tanh_fast(g0);
    float cn1 = sigm(f1g) * c1 + sigm(i1) * tanh_fast(g1);
    float hn0 = sigm(o0) * tanh_fast(cn0);
    float hn1 = sigm(o1) * tanh_fast(cn1);
    c0 = cn0; c1 = cn1;

    // packed h: one 8B agent-scope store per thread
    {
      unsigned short h0 = f2bf(hn0);
      unsigned short l0 = f2bf(hn0 - bf2f(h0));
      unsigned short h1 = f2bf(hn1);
      unsigned short l1 = f2bf(hn1 - bf2f(h1));
      unsigned pk0 = (unsigned)h0 | ((unsigned)l0 << 16);
      unsigned pk1 = (unsigned)h1 | ((unsigned)l1 << 16);
      unsigned long long pv = (unsigned long long)pk0 | ((unsigned long long)pk1 << 32);
      __hip_atomic_store(
          (unsigned long long*)(hb_g + (size_t)(p ^ 1) * (GM * Hv) + gr * Hv + cb * 32 + gj),
          pv, __ATOMIC_RELAXED, __HIP_MEMORY_SCOPE_AGENT);
    }
    // enc_out fp16 pair
    {
      __half2 h2;
      h2.x = __float2half(hn0);
      h2.y = __float2half(hn1);
      *(__half2*)(enc_out + ((size_t)(g * GM + gr) * Sv + s) * Hv + cb * 32 + gj) = h2;
    }

    // ---- prefetch next step's P gather (hidden under the barrier wait)
    {
      int sn = (s + 1 < Sv) ? s + 1 : Sv - 1;
#pragma unroll
      for (int rr = 0; rr < 4; ++rr) {
        int tk  = enc_in[(g * GM + r0 + rr) * Sv + sn];
        px0[rr] = P[(size_t)tk * 2048 + ncol];
        px1[rr] = P[(size_t)tk * 2048 + ncol + 16];
      }
    }

    // ---- flag-line barrier: drain stores, store own flag, 64-lane poll
    __syncthreads();                 // s_waitcnt vmcnt(0): h stores at coherence point
    if (wave == 0) {
      if (lane == 0)
        __hip_atomic_store(&flg[cb], (unsigned)(s + 1),
                           __ATOMIC_RELAXED, __HIP_MEMORY_SCOPE_AGENT);
      const unsigned tgt = (unsigned)(s + 1);
      while (true) {
        unsigned f = __hip_atomic_load(&flg[lane & 15],
                                       __ATOMIC_RELAXED, __HIP_MEMORY_SCOPE_AGENT);
        if (__all((int)(f >= tgt))) break;
        __builtin_amdgcn_s_sleep(1);
      }
    }
    __syncthreads();
  }
}

// One wg per batch row: scores = enc_out[b] @ We, softmax over S, ctx, then
// pa/pt dots tiled over T. fp32 math, fp16 enc_out reads (16B score loads).
__global__ __launch_bounds__(256)
void attn_out(const __half* __restrict__ enc_out, const float* __restrict__ Wf,
              const float* __restrict__ Wa, const float* __restrict__ ba,
              const float* __restrict__ Wt, const float* __restrict__ bt,
              float* __restrict__ out)
{
  __shared__ float We[512];
  __shared__ float sc[256];
  __shared__ float ctx[512];
  __shared__ float red[8];
  const int tid = threadIdx.x;
  const int b   = blockIdx.x;
  const int wv  = tid >> 6;
  const int ln  = tid & 63;

  We[tid] = Wf[tid];
  We[tid + 256] = Wf[tid + 256];
  __syncthreads();

  // score for s = tid; 16B (half8) loads
  const uint4* r4 = (const uint4*)(enc_out + ((size_t)b * Sv + tid) * Hv);
  float a = 0.f;
#pragma unroll 4
  for (int k = 0; k < 64; ++k) {
    uint4 v = r4[k];
    float2 f0 = __half22float2(__builtin_bit_cast(__half2, v.x));
    float2 f1 = __half22float2(__builtin_bit_cast(__half2, v.y));
    float2 f2 = __half22float2(__builtin_bit_cast(__half2, v.z));
    float2 f3 = __half22float2(__builtin_bit_cast(__half2, v.w));
    const float* w = &We[8 * k];
    a += f0.x * w[0] + f0.y * w[1] + f1.x * w[2] + f1.y * w[3]
       + f2.x * w[4] + f2.y * w[5] + f3.x * w[6] + f3.y * w[7];
  }

  // softmax over S=256
  float m = a;
  for (int off = 32; off; off >>= 1) m = fmaxf(m, __shfl_down(m, off));
  if (ln == 0) red[wv] = m;
  __syncthreads();
  if (tid == 0) red[4] = fmaxf(fmaxf(red[0], red[1]), fmaxf(red[2], red[3]));
  __syncthreads();
  float e = __expf(a - red[4]);
  float ssum = e;
  for (int off = 32; off; off >>= 1) ssum += __shfl_down(ssum, off);
  if (ln == 0) red[wv] = ssum;
  __syncthreads();
  if (tid == 0) red[5] = red[0] + red[1] + red[2] + red[3];
  __syncthreads();
  sc[tid] = e * (1.f / red[5]);
  __syncthreads();

  // ctx[h]: thread owns cols 2*tid, 2*tid+1 (coalesced across threads)
  {
    float a0 = 0.f, a1 = 0.f;
    const __half2* base = (const __half2*)(enc_out + (size_t)b * Sv * Hv) + tid;
#pragma unroll 4
    for (int s2 = 0; s2 < Sv; ++s2) {
      float2 f = __half22float2(base[s2 * (Hv / 2)]);
      float w = sc[s2];
      a0 += w * f.x;
      a1 += w * f.y;
    }
    ctx[2 * tid] = a0;
    ctx[2 * tid + 1] = a1;
  }
  __syncthreads();

  // pa (8) and pt (80) dots; outputs constant over T -> tile
  if (tid < 88) {
    const float* wr = (tid < 8) ? (Wa + tid * Hv) : (Wt + (tid - 8) * Hv);
    float o = (tid < 8) ? ba[tid] : bt[tid - 8];
    for (int k = 0; k < Hv; ++k) o += ctx[k] * wr[k];
    if (tid < 8) {
      float* o0 = out + (size_t)b * Tv * 8;
#pragma unroll
      for (int t = 0; t < Tv; ++t) o0[t * 8 + tid] = o;
    } else {
      int n = tid - 8;
      float* o1 = out + 65536 + (size_t)b * Tv * 80;
#pragma unroll
      for (int t = 0; t < Tv; ++t) o1[t * 80 + n] = o;
    }
  }
}

extern "C" void kernel_launch(void* const* d_in, const int* in_sizes, int n_in,
                              void* d_out, int out_size, void* d_ws, size_t ws_size,
                              hipStream_t stream)
{
  (void)in_sizes; (void)n_in; (void)out_size; (void)ws_size;
  const int*   enc_in = (const int*)d_in[0];
  const float* embed  = (const float*)d_in[2];
  const float* Wi     = (const float*)d_in[3];
  const float* Wh     = (const float*)d_in[4];
  const float* be     = (const float*)d_in[5];
  const float* Wa     = (const float*)d_in[11];
  const float* ba     = (const float*)d_in[12];
  const float* Wt     = (const float*)d_in[13];
  const float* bt     = (const float*)d_in[14];
  const float* Wf     = (const float*)d_in[15];
  // d_in[1] decoder_target, [6..10] decoder weights, [16] bf: dead code

  char* ws = (char*)d_ws;
  unsigned* flags  = (unsigned*)ws;                         // 16 groups x 16 flags = 1KB
  unsigned* hbuf   = (unsigned*)(ws + 1024);                // 16 x 2 x 16x512 packed = 1MB
  float*    P      = (float*)(ws + 1024 + (1u << 20));      // 1000 x 2048 fp32 = 8MB
  __half*   encout = (__half*)(ws + 1024 + (1u << 20) + (8u << 20)); // 64MB

  hipMemsetAsync(d_ws, 0, 1024 + (1u << 20), stream);       // zero flags + h0

  build_P<<<dim3(250), dim3(256), 0, stream>>>(embed, Wi, be, P);
  lstm_enc<<<dim3(256), dim3(256), 0, stream>>>(enc_in, P, Wh, flags, hbuf, encout);
  attn_out<<<dim3(256), dim3(256), 0, stream>>>(encout, Wf, Wa, ba, Wt, bt, (float*)d_out);
}

// Round 4
// 941.007 us; speedup vs baseline: 2.0200x; 2.0200x over previous
//
#include <hip/hip_runtime.h>
#include <hip/hip_fp16.h>

// B=256,S=256,T=32,H=512,E=128,V=1000,A=8,NT=80.
// Math: decoder is dead code (softmax shift-invariance over S) -> outputs are
// pa/pt tiled over T. Remaining: 256 serial LSTM steps + attention readout.
//
// Structure: 16 batch-groups x (16 rows, 16 wgs); each wg owns 128 z-cols with
// Wh weights in registers (bf16); h exchanged through fabric; activations
// hi/lo bf16 split (2 MFMAs ~ fp32); per-group flag barrier each step.
// R1: __threadfence -> buffer_wbl2+inv nuked L2 every step. Fixed (2x).
// R2/R3: pinned at 6.7us/step regardless of barrier protocol or MFMA count ->
// floor is the 16 per-thread 8B atomic h-loads (conservative per-op waits).
// R4: h-stage via pipelined global_load_dwordx4 sc0 sc1 (coherent, 8/thread,
// one vmcnt(0)); flag stored right after the h-drain barrier; enc_out + P
// prefetch issued UNDER the poll; launch_bounds(256,1).

#define Bv 256
#define Sv 256
#define Tv 32
#define Hv 512
#define KT 16          // k-tiles of 32 over K=512 (h only; x-part via P gather)
#define LDSA 520       // padded k-stride (shorts)
#define GM 16          // batch rows per group
#define WPG 16         // workgroups per group

typedef __attribute__((ext_vector_type(8))) short bf16x8;
typedef __attribute__((ext_vector_type(4))) float f32x4;
typedef __attribute__((ext_vector_type(4))) unsigned uint4v;

__device__ __forceinline__ unsigned short f2bf(float x) {   // RNE fp32->bf16
  unsigned u = __builtin_bit_cast(unsigned, x);
  u += 0x7fffu + ((u >> 16) & 1u);
  return (unsigned short)(u >> 16);
}
__device__ __forceinline__ float bf2f(unsigned short h) {
  unsigned u = ((unsigned)h) << 16;
  return __builtin_bit_cast(float, u);
}
__device__ __forceinline__ float sigm(float x) { return 1.0f / (1.0f + __expf(-x)); }
__device__ __forceinline__ float tanh_fast(float x) {
  x = fminf(15.f, fmaxf(-15.f, x));
  float e = __expf(2.f * x);
  return (e - 1.f) / (e + 1.f);
}

// Coherent (device-scope) 16B load: bypasses L1+L2, pipelines like any vmem op.
__device__ __forceinline__ uint4v ld_b128_sys(const void* p) {
  uint4v r;
  asm volatile("global_load_dwordx4 %0, %1, off sc0 sc1" : "=v"(r) : "v"(p));
  return r;
}

// ---- P[v][n] = sum_k embed[v][k]*Wi[n][k] + be[n], fp32. 250 blocks x 4 tokens.
__global__ __launch_bounds__(256)
void build_P(const float* __restrict__ embed, const float* __restrict__ Wi,
             const float* __restrict__ be, float* __restrict__ P)
{
  __shared__ float ev[4][128];
  const int tid = threadIdx.x;
  const int v0  = blockIdx.x * 4;
#pragma unroll
  for (int i = 0; i < 2; ++i) {
    int e = tid + i * 256;
    ev[e >> 7][e & 127] = embed[(v0 + (e >> 7)) * 128 + (e & 127)];
  }
  __syncthreads();
#pragma unroll 1
  for (int cc = 0; cc < 8; ++cc) {
    int n = cc * 256 + tid;
    float b = be[n];
    float a0 = b, a1 = b, a2 = b, a3 = b;
    const f32x4* w = (const f32x4*)(Wi + n * 128);
#pragma unroll
    for (int k4 = 0; k4 < 32; ++k4) {
      f32x4 wv = w[k4];
#pragma unroll
      for (int j = 0; j < 4; ++j) {
        float wj = wv[j];
        int k = k4 * 4 + j;
        a0 += wj * ev[0][k]; a1 += wj * ev[1][k];
        a2 += wj * ev[2][k]; a3 += wj * ev[3][k];
      }
    }
    P[(size_t)(v0 + 0) * 2048 + n] = a0;
    P[(size_t)(v0 + 1) * 2048 + n] = a1;
    P[(size_t)(v0 + 2) * 2048 + n] = a2;
    P[(size_t)(v0 + 3) * 2048 + n] = a3;
  }
}

// hbuf: per group g, parity p: [16 rows][512 cols] packed (bf16_hi | bf16_lo<<16).
// flags: flags[g*16 + cb] = last step this wg finished (one 64B line per group).
__global__ __launch_bounds__(256, 1)
void lstm_enc(const int* __restrict__ enc_in, const float* __restrict__ P,
              const float* __restrict__ Wh,
              unsigned* __restrict__ flags, unsigned* __restrict__ hbuf,
              __half* __restrict__ enc_out)
{
  __shared__ __attribute__((aligned(16))) short Ahi[GM][LDSA];
  __shared__ __attribute__((aligned(16))) short Alo[GM][LDSA];
  __shared__ float zbuf[4][GM][37];

  const int tid  = threadIdx.x;
  const int wg   = blockIdx.x;
  const int g    = wg & 15;   // group (members share wg%8 -> same XCD heuristically; perf only)
  const int cb   = wg >> 4;   // column block: owns z-cols [q*512 + cb*32, +32) per gate q
  const int wave = tid >> 6;  // wave == gate q (0=i,1=f,2=g,3=o)
  const int lane = tid & 63;
  const int m16  = lane & 15;
  const int qd   = lane >> 4;

  // ---- Wh fragments in registers: lane holds W'[n][k] for
  // n = wave*512 + cb*32 + nt*16 + m16, k = kt*32 + qd*8 + j (j=0..7).
  bf16x8 wf[KT][2];
#pragma unroll
  for (int kt = 0; kt < KT; ++kt) {
#pragma unroll
    for (int nt = 0; nt < 2; ++nt) {
      int n  = wave * 512 + cb * 32 + nt * 16 + m16;
      int k0 = kt * 32 + qd * 8;
      const float* src = Wh + (size_t)n * Hv + k0;
      f32x4 f0 = *(const f32x4*)(src);
      f32x4 f1 = *(const f32x4*)(src + 4);
      bf16x8 w;
      w[0] = (short)f2bf(f0[0]); w[1] = (short)f2bf(f0[1]);
      w[2] = (short)f2bf(f0[2]); w[3] = (short)f2bf(f0[3]);
      w[4] = (short)f2bf(f1[0]); w[5] = (short)f2bf(f1[1]);
      w[6] = (short)f2bf(f1[2]); w[7] = (short)f2bf(f1[3]);
      wf[kt][nt] = w;
    }
  }

  // gates-phase mapping: thread owns (row gr, cols gj, gj+1); c-state in regs
  const int gr = tid >> 4;
  const int gj = (tid & 15) * 2;
  float c0 = 0.f, c1 = 0.f;

  unsigned* hb_g = hbuf + (size_t)g * (2 * GM * Hv);
  unsigned* flg  = flags + g * 16;

  // ---- P prefetch for s=0 (acc-layout rows r0..r0+3, cols ncol, ncol+16)
  const int r0   = qd * 4;
  const int ncol = wave * 512 + cb * 32 + m16;
  float px0[4], px1[4];
#pragma unroll
  for (int rr = 0; rr < 4; ++rr) {
    int tk  = enc_in[(g * GM + r0 + rr) * Sv + 0];
    px0[rr] = P[(size_t)tk * 2048 + ncol];
    px1[rr] = P[(size_t)tk * 2048 + ncol + 16];
  }

#pragma unroll 1
  for (int s = 0; s < Sv; ++s) {
    const int p = s & 1;

    // ---- stage h (parity p): 8 pipelined coherent b128 loads -> unpack -> LDS
    {
      const unsigned* hsrc = hb_g + (size_t)p * (GM * Hv);
      uint4v r8[8];
#pragma unroll
      for (int j = 0; j < 8; ++j)
        r8[j] = ld_b128_sys((const void*)(hsrc + (j * 256 + tid) * 4));
      asm volatile("s_waitcnt vmcnt(0)"
                   : "+v"(r8[0]), "+v"(r8[1]), "+v"(r8[2]), "+v"(r8[3]),
                     "+v"(r8[4]), "+v"(r8[5]), "+v"(r8[6]), "+v"(r8[7])
                   :: "memory");
      const int col = (4 * tid) & 511;
      const int rb  = tid >> 7;
#pragma unroll
      for (int j = 0; j < 8; ++j) {
        int r = j * 2 + rb;
        unsigned w0 = r8[j][0], w1 = r8[j][1], w2 = r8[j][2], w3 = r8[j][3];
        unsigned hi01 = (w0 & 0xffffu) | (w1 << 16);
        unsigned hi23 = (w2 & 0xffffu) | (w3 << 16);
        unsigned lo01 = (w0 >> 16) | (w1 & 0xffff0000u);
        unsigned lo23 = (w2 >> 16) | (w3 & 0xffff0000u);
        uint2 hv; hv.x = hi01; hv.y = hi23;
        uint2 lv; lv.x = lo01; lv.y = lo23;
        *(uint2*)&Ahi[r][col] = hv;
        *(uint2*)&Alo[r][col] = lv;
      }
    }
    __syncthreads();

    // ---- MFMA: z_h = (A_hi + A_lo) @ Wh^T
    f32x4 acc0 = {0.f, 0.f, 0.f, 0.f};
    f32x4 acc1 = {0.f, 0.f, 0.f, 0.f};
#pragma unroll
    for (int kt = 0; kt < KT; ++kt) {
      bf16x8 ah = *(const bf16x8*)&Ahi[m16][kt * 32 + qd * 8];
      bf16x8 al = *(const bf16x8*)&Alo[m16][kt * 32 + qd * 8];
      acc0 = __builtin_amdgcn_mfma_f32_16x16x32_bf16(ah, wf[kt][0], acc0, 0, 0, 0);
      acc0 = __builtin_amdgcn_mfma_f32_16x16x32_bf16(al, wf[kt][0], acc0, 0, 0, 0);
      acc1 = __builtin_amdgcn_mfma_f32_16x16x32_bf16(ah, wf[kt][1], acc1, 0, 0, 0);
      acc1 = __builtin_amdgcn_mfma_f32_16x16x32_bf16(al, wf[kt][1], acc1, 0, 0, 0);
    }
    // C/D layout: col = lane&15, row = (lane>>4)*4 + reg; add fp32 x-part (P)
#pragma unroll
    for (int rr = 0; rr < 4; ++rr) {
      zbuf[wave][r0 + rr][m16]      = acc0[rr] + px0[rr];
      zbuf[wave][r0 + rr][16 + m16] = acc1[rr] + px1[rr];
    }
    __syncthreads();

    // ---- gates for (gr, gj), (gr, gj+1)
    float i0 = zbuf[0][gr][gj], i1 = zbuf[0][gr][gj + 1];
    float f0g = zbuf[1][gr][gj], f1g = zbuf[1][gr][gj + 1];
    float g0 = zbuf[2][gr][gj], g1 = zbuf[2][gr][gj + 1];
    float o0 = zbuf[3][gr][gj], o1 = zbuf[3][gr][gj + 1];
    float cn0 = sigm(f0g) * c0 + sigm(i0) * tanh_fast(g0);
    float cn1 = sigm(f1g) * c1 + sigm(i1) * tanh_fast(g1);
    float hn0 = sigm(o0) * tanh_fast(cn0);
    float hn1 = sigm(o1) * tanh_fast(cn1);
    c0 = cn0; c1 = cn1;

    float hn0s = hn0, hn1s = hn1;   // keep for enc_out below

    // packed h: one 8B agent-scope store per thread
    {
      unsigned short h0 = f2bf(hn0);
      unsigned short l0 = f2bf(hn0 - bf2f(h0));
      unsigned short h1 = f2bf(hn1);
      unsigned short l1 = f2bf(hn1 - bf2f(h1));
      unsigned pk0 = (unsigned)h0 | ((unsigned)l0 << 16);
      unsigned pk1 = (unsigned)h1 | ((unsigned)l1 << 16);
      unsigned long long pv = (unsigned long long)pk0 | ((unsigned long long)pk1 << 32);
      __hip_atomic_store(
          (unsigned long long*)(hb_g + (size_t)(p ^ 1) * (GM * Hv) + gr * Hv + cb * 32 + gj),
          pv, __ATOMIC_RELAXED, __HIP_MEMORY_SCOPE_AGENT);
    }

    // ---- barrier drains ALL waves' h stores (compiler emits vmcnt(0) before
    // s_barrier), then flag goes out IMMEDIATELY; enc_out + P prefetch issue
    // under the poll.
    __syncthreads();
    if (tid == 0)
      __hip_atomic_store(&flg[cb], (unsigned)(s + 1),
                         __ATOMIC_RELAXED, __HIP_MEMORY_SCOPE_AGENT);

    // enc_out fp16 pair (drains at the post-poll barrier)
    {
      __half2 h2;
      h2.x = __float2half(hn0s);
      h2.y = __float2half(hn1s);
      *(__half2*)(enc_out + ((size_t)(g * GM + gr) * Sv + s) * Hv + cb * 32 + gj) = h2;
    }
    // next step's P gather (hidden under the poll)
    {
      int sn = (s + 1 < Sv) ? s + 1 : Sv - 1;
#pragma unroll
      for (int rr = 0; rr < 4; ++rr) {
        int tk  = enc_in[(g * GM + r0 + rr) * Sv + sn];
        px0[rr] = P[(size_t)tk * 2048 + ncol];
        px1[rr] = P[(size_t)tk * 2048 + ncol + 16];
      }
    }

    // ---- 64-lane parallel poll of the group's 16 flags
    if (wave == 0) {
      const unsigned tgt = (unsigned)(s + 1);
      while (true) {
        unsigned f = __hip_atomic_load(&flg[lane & 15],
                                       __ATOMIC_RELAXED, __HIP_MEMORY_SCOPE_AGENT);
        if (__all((int)(f >= tgt))) break;
        __builtin_amdgcn_s_sleep(1);
      }
    }
    __syncthreads();
  }
}

// One wg per batch row: scores = enc_out[b] @ We, softmax over S, ctx, then
// pa/pt dots tiled over T. fp32 math, fp16 enc_out reads (16B score loads).
__global__ __launch_bounds__(256)
void attn_out(const __half* __restrict__ enc_out, const float* __restrict__ Wf,
              const float* __restrict__ Wa, const float* __restrict__ ba,
              const float* __restrict__ Wt, const float* __restrict__ bt,
              float* __restrict__ out)
{
  __shared__ float We[512];
  __shared__ float sc[256];
  __shared__ float ctx[512];
  __shared__ float red[8];
  const int tid = threadIdx.x;
  const int b   = blockIdx.x;
  const int wv  = tid >> 6;
  const int ln  = tid & 63;

  We[tid] = Wf[tid];
  We[tid + 256] = Wf[tid + 256];
  __syncthreads();

  // score for s = tid; 16B (half8) loads
  const uint4* r4 = (const uint4*)(enc_out + ((size_t)b * Sv + tid) * Hv);
  float a = 0.f;
#pragma unroll 4
  for (int k = 0; k < 64; ++k) {
    uint4 v = r4[k];
    float2 f0 = __half22float2(__builtin_bit_cast(__half2, v.x));
    float2 f1 = __half22float2(__builtin_bit_cast(__half2, v.y));
    float2 f2 = __half22float2(__builtin_bit_cast(__half2, v.z));
    float2 f3 = __half22float2(__builtin_bit_cast(__half2, v.w));
    const float* w = &We[8 * k];
    a += f0.x * w[0] + f0.y * w[1] + f1.x * w[2] + f1.y * w[3]
       + f2.x * w[4] + f2.y * w[5] + f3.x * w[6] + f3.y * w[7];
  }

  // softmax over S=256
  float m = a;
  for (int off = 32; off; off >>= 1) m = fmaxf(m, __shfl_down(m, off));
  if (ln == 0) red[wv] = m;
  __syncthreads();
  if (tid == 0) red[4] = fmaxf(fmaxf(red[0], red[1]), fmaxf(red[2], red[3]));
  __syncthreads();
  float e = __expf(a - red[4]);
  float ssum = e;
  for (int off = 32; off; off >>= 1) ssum += __shfl_down(ssum, off);
  if (ln == 0) red[wv] = ssum;
  __syncthreads();
  if (tid == 0) red[5] = red[0] + red[1] + red[2] + red[3];
  __syncthreads();
  sc[tid] = e * (1.f / red[5]);
  __syncthreads();

  // ctx[h]: thread owns cols 2*tid, 2*tid+1 (coalesced across threads)
  {
    float a0 = 0.f, a1 = 0.f;
    const __half2* base = (const __half2*)(enc_out + (size_t)b * Sv * Hv) + tid;
#pragma unroll 4
    for (int s2 = 0; s2 < Sv; ++s2) {
      float2 f = __half22float2(base[s2 * (Hv / 2)]);
      float w = sc[s2];
      a0 += w * f.x;
      a1 += w * f.y;
    }
    ctx[2 * tid] = a0;
    ctx[2 * tid + 1] = a1;
  }
  __syncthreads();

  // pa (8) and pt (80) dots; outputs constant over T -> tile
  if (tid < 88) {
    const float* wr = (tid < 8) ? (Wa + tid * Hv) : (Wt + (tid - 8) * Hv);
    float o = (tid < 8) ? ba[tid] : bt[tid - 8];
    for (int k = 0; k < Hv; ++k) o += ctx[k] * wr[k];
    if (tid < 8) {
      float* o0 = out + (size_t)b * Tv * 8;
#pragma unroll
      for (int t = 0; t < Tv; ++t) o0[t * 8 + tid] = o;
    } else {
      int n = tid - 8;
      float* o1 = out + 65536 + (size_t)b * Tv * 80;
#pragma unroll
      for (int t = 0; t < Tv; ++t) o1[t * 80 + n] = o;
    }
  }
}

extern "C" void kernel_launch(void* const* d_in, const int* in_sizes, int n_in,
                              void* d_out, int out_size, void* d_ws, size_t ws_size,
                              hipStream_t stream)
{
  (void)in_sizes; (void)n_in; (void)out_size; (void)ws_size;
  const int*   enc_in = (const int*)d_in[0];
  const float* embed  = (const float*)d_in[2];
  const float* Wi     = (const float*)d_in[3];
  const float* Wh     = (const float*)d_in[4];
  const float* be     = (const float*)d_in[5];
  const float* Wa     = (const float*)d_in[11];
  const float* ba     = (const float*)d_in[12];
  const float* Wt     = (const float*)d_in[13];
  const float* bt     = (const float*)d_in[14];
  const float* Wf     = (const float*)d_in[15];
  // d_in[1] decoder_target, [6..10] decoder weights, [16] bf: dead code

  char* ws = (char*)d_ws;
  unsigned* flags  = (unsigned*)ws;                         // 16 groups x 16 flags = 1KB
  unsigned* hbuf   = (unsigned*)(ws + 1024);                // 16 x 2 x 16x512 packed = 1MB
  float*    P      = (float*)(ws + 1024 + (1u << 20));      // 1000 x 2048 fp32 = 8MB
  __half*   encout = (__half*)(ws + 1024 + (1u << 20) + (8u << 20)); // 64MB

  hipMemsetAsync(d_ws, 0, 1024 + (1u << 20), stream);       // zero flags + h0

  build_P<<<dim3(250), dim3(256), 0, stream>>>(embed, Wi, be, P);
  lstm_enc<<<dim3(256), dim3(256), 0, stream>>>(enc_in, P, Wh, flags, hbuf, encout);
  attn_out<<<dim3(256), dim3(256), 0, stream>>>(encout, Wf, Wa, ba, Wt, bt, (float*)d_out);
}